// Round 14
// baseline (246.379 us; speedup 1.0000x reference)
//
#include <hip/hip_runtime.h>
#include <hip/hip_bf16.h>

#define B_   16384
#define KIN  512
#define NE   8
#define HE   256
#define NT   2
#define NO   64

using f32x4  = __attribute__((ext_vector_type(4))) float;
using short8 = __attribute__((ext_vector_type(8))) short;

typedef const __attribute__((address_space(1))) void* gas_ptr;
typedef __attribute__((address_space(3))) void* las_ptr;

__device__ __forceinline__ float bf2f(unsigned short u) {
    union { unsigned int i; float f; } c; c.i = ((unsigned int)u) << 16; return c.f;
}
__device__ __forceinline__ unsigned short f2bf(float f) {
    union { __hip_bfloat16 h; unsigned short u; } c; c.h = __float2bfloat16(f); return c.u;
}

// ---------------- K_W: all weight preprocessing in one launch (r10 version) ----------------
__global__ __launch_bounds__(256) void k_cvt_w(const float* __restrict__ We,
                                               const float* __restrict__ Wt,
                                               const float* __restrict__ Wg,
                                               unsigned short* __restrict__ Wb,
                                               unsigned short* __restrict__ WtT,
                                               unsigned short* __restrict__ WgT) {
    int bid = blockIdx.x;
    int tid = threadIdx.x;
    if (bid < 256) {
        __shared__ float tile[64][65];
        int e = bid >> 5, rem = bid & 31, kt = rem >> 2, ht = rem & 3;
        const float* src = We + e * (KIN * HE) + (kt * 64) * HE + ht * 64;
        for (int it = 0; it < 16; ++it) {
            int idx = tid + it * 256;
            int i = idx >> 6, j = idx & 63;
            tile[i][j] = src[i * HE + j];
        }
        __syncthreads();
        unsigned short* dst = Wb + (size_t)(e * HE + ht * 64) * KIN + kt * 64;
        for (int it = 0; it < 16; ++it) {
            int idx = tid + it * 256;
            int i = idx >> 6, j = idx & 63;
            dst[i * KIN + j] = f2bf(tile[j][i]);
        }
    } else if (bid < 264) {
        __shared__ float tile[64][65];
        int b = bid - 256;
        int t = b >> 2, kt = b & 3, k0 = kt * 64;
        const float* src = Wt + t * (HE * NO) + k0 * NO;
        for (int it = 0; it < 16; ++it) {
            int idx = tid + it * 256;
            int i = idx >> 6, j = idx & 63;
            tile[i][j] = src[i * NO + j];
        }
        __syncthreads();
        unsigned short* dst = WtT + (size_t)t * NO * HE + k0;
        for (int it = 0; it < 16; ++it) {
            int idx = tid + it * 256;
            int o = idx >> 6, j = idx & 63;
            dst[o * HE + j] = f2bf(tile[j][o]);
        }
    } else {
        int n = tid >> 4;
        int kb = (tid & 15) * 32;
        int t = n >> 3, e = n & 7;
        const float* src = Wg + t * (KIN * NE) + e;
        for (int j = 0; j < 32; ++j) {
            int k = kb + j;
            WgT[n * KIN + k] = f2bf(src[k * NE]);
        }
    }
}

// ---------------- K_MEGA: r10 structure + expert-pair A-reuse ----------------
// 64-row stripe, 512 threads (8 waves), grid 256 = 1 block/CU.
// Step order s = ep*16 + kt*2 + ei (pair-major): consecutive steps hit experts
// (2ep, 2ep+1) at the SAME kt -> A frags load on even steps only, persist in
// a2[2][4] across the pair. A LDS reads: 768 -> 512 b128/wave (-33%).
// Staging/ring/vmcnt identical to r10: per-wave 32-row B slices, 2 slots x 32KB,
// slot = s&1, stage(s+1) then vmcnt(4). Barrier-free loop (r10-verified).
__global__ __launch_bounds__(512, 2) void k_mega(const float* __restrict__ xv,
                                                 const unsigned short* __restrict__ Wb,
                                                 const float* __restrict__ be,
                                                 const unsigned short* __restrict__ WgT,
                                                 const float* __restrict__ bg,
                                                 const unsigned short* __restrict__ WtT,
                                                 const float* __restrict__ bt,
                                                 float* __restrict__ out) {
    __shared__ __align__(16) char smem[135424];
    unsigned short* Xs  = (unsigned short*)smem;             // 65536 B, swizzled
    unsigned short* Bs  = (unsigned short*)(smem + 65536);   // 65536 B = 2 slots x 32KB
    float*          gs  = (float*)(smem + 131072);           // 4352 B, row stride 17
    unsigned short* TIs = (unsigned short*)smem;             // overlay after loop

    int tid = threadIdx.x, lane = tid & 63, wav = tid >> 6;
    int l15 = lane & 15, l4 = lane >> 4;
    int swz = (l15 & 7) * 8;                 // read-side XOR (shorts)
    int wv32 = wav * 32;                     // wave's h-col slice
    int r0 = blockIdx.x * 64;

    int row_off = lane >> 3;                 // 0..7
    int sco = ((lane & 7) ^ row_off) * 8;    // pre-swizzled source chunk (shorts)

    // wave stages ONLY its own 32-row slice of step-s's expert tile into slot s&1
    // s decode: ep = s>>4, kt = (s>>1)&7, ei = s&1, e = 2*ep+ei
    auto stage_b = [&](int s) {
        int ep = s >> 4, kt = (s >> 1) & 7, ei = s & 1;
        int e = ep * 2 + ei, b = s & 1;
        const unsigned short* Wbase = Wb + (size_t)(e * 256 + wv32) * KIN + kt * 64;
        #pragma unroll
        for (int i = 0; i < 4; ++i) {
            int rb = i * 8;
            __builtin_amdgcn_global_load_lds(
                (gas_ptr)(Wbase + (size_t)(rb + row_off) * KIN + sco),
                (las_ptr)(Bs + b * 16384 + (wv32 + rb) * 64), 16, 0, 0);
        }
    };

    // ---- prologue: X fp32 -> bf16 -> swizzled LDS (reg-staged)
    #pragma unroll
    for (int j = 0; j < 8; ++j) {
        int row = wav * 8 + j;
        const float4* src = (const float4*)(xv + (size_t)(r0 + row) * KIN) + lane * 2;
        float4 xa = src[0], xb = src[1];
        union { short8 v; unsigned short s[8]; } cv;
        cv.s[0] = f2bf(xa.x); cv.s[1] = f2bf(xa.y); cv.s[2] = f2bf(xa.z); cv.s[3] = f2bf(xa.w);
        cv.s[4] = f2bf(xb.x); cv.s[5] = f2bf(xb.y); cv.s[6] = f2bf(xb.z); cv.s[7] = f2bf(xb.w);
        *(short8*)(Xs + row * KIN + ((lane ^ (row & 7)) * 8)) = cv.v;
    }
    asm volatile("s_waitcnt lgkmcnt(0)" ::: "memory");
    asm volatile("s_barrier" ::: "memory");          // Xs visible to all waves

    stage_b(0);                                      // lands during gates phase

    // ---- gates: softmax(X @ WgT^T + bg) -> gs  (waves w, w+4 duplicate; benign)
    {
        int m0w = (wav & 3) * 16;
        f32x4 ga = {0.f, 0.f, 0.f, 0.f};
        #pragma unroll
        for (int kk = 0; kk < 16; ++kk) {
            short8 a = *(const short8*)(Xs + (m0w + l15) * KIN + ((kk * 32 + l4 * 8) ^ swz));
            short8 b = *(const short8*)(WgT + (size_t)l15 * KIN + kk * 32 + l4 * 8);
            ga = __builtin_amdgcn_mfma_f32_16x16x32_bf16(a, b, ga, 0, 0, 0);
        }
        float bias = bg[l15];
        #pragma unroll
        for (int r = 0; r < 4; ++r) {
            float v = ga[r] + bias;
            float m = v;
            m = fmaxf(m, __shfl_xor(m, 1));
            m = fmaxf(m, __shfl_xor(m, 2));
            m = fmaxf(m, __shfl_xor(m, 4));
            float p = __expf(v - m);
            float su = p;
            su += __shfl_xor(su, 1);
            su += __shfl_xor(su, 2);
            su += __shfl_xor(su, 4);
            gs[(m0w + l4 * 4 + r) * 17 + l15] = p / su;
        }
    }
    asm volatile("s_waitcnt lgkmcnt(0)" ::: "memory");
    asm volatile("s_barrier" ::: "memory");          // gs visible to all waves

    // ---- expert loop state: acc[expert-in-pair][mf][nf], ti accumulators
    f32x4 acc[2][4][2];
    f32x4 ti0[4][2], ti1[4][2];
    f32x4 z = {0.f, 0.f, 0.f, 0.f};
    #pragma unroll
    for (int mf = 0; mf < 4; ++mf)
        #pragma unroll
        for (int nf = 0; nf < 2; ++nf) {
            acc[0][mf][nf] = z; acc[1][mf][nf] = z;
            ti0[mf][nf] = z; ti1[mf][nf] = z;
        }

    auto fold = [&](int e, f32x4 (&ac)[4][2]) {
        float b0 = be[e * 256 + wv32 + l15];
        float b1 = be[e * 256 + wv32 + 16 + l15];
        #pragma unroll
        for (int mf = 0; mf < 4; ++mf) {
            #pragma unroll
            for (int r = 0; r < 4; ++r) {
                int rloc = mf * 16 + l4 * 4 + r;
                float g0 = gs[rloc * 17 + e];
                float g1 = gs[rloc * 17 + 8 + e];
                float h0 = fmaxf(ac[mf][0][r] + b0, 0.f);
                float h1 = fmaxf(ac[mf][1][r] + b1, 0.f);
                ti0[mf][0][r] = fmaf(g0, h0, ti0[mf][0][r]);
                ti0[mf][1][r] = fmaf(g0, h1, ti0[mf][1][r]);
                ti1[mf][0][r] = fmaf(g1, h0, ti1[mf][0][r]);
                ti1[mf][1][r] = fmaf(g1, h1, ti1[mf][1][r]);
                ac[mf][0][r] = 0.f;
                ac[mf][1][r] = 0.f;
            }
        }
    };

    // ---- main loop: barrier-free, per-wave vmcnt pacing; pair-major order
    short8 a2[2][4];                                 // persistent A frags [kk][mf]
    #pragma unroll 16
    for (int s = 0; s < 64; ++s) {
        if (s < 63) {
            stage_b(s + 1);
            asm volatile("s_waitcnt vmcnt(4)" ::: "memory");  // batch s landed
        } else {
            asm volatile("s_waitcnt vmcnt(0)" ::: "memory");
        }
        int kt = (s >> 1) & 7, ei = s & 1, b = s & 1;
        int k0 = kt * 64;
        __builtin_amdgcn_s_setprio(1);
        #pragma unroll
        for (int kk = 0; kk < 2; ++kk) {
            if (ei == 0) {                           // load A only on even steps
                int kca = (k0 + kk * 32 + l4 * 8) ^ swz;
                #pragma unroll
                for (int mf = 0; mf < 4; ++mf)
                    a2[kk][mf] = *(const short8*)(Xs + (mf * 16 + l15) * KIN + kca);
            }
            short8 bb[2];
            int kcb = (kk * 32 + l4 * 8) ^ swz;
            #pragma unroll
            for (int nf = 0; nf < 2; ++nf)
                bb[nf] = *(const short8*)(Bs + b * 16384 + (wv32 + nf * 16 + l15) * 64 + kcb);
            #pragma unroll
            for (int mf = 0; mf < 4; ++mf)
                #pragma unroll
                for (int nf = 0; nf < 2; ++nf)
                    acc[ei][mf][nf] = __builtin_amdgcn_mfma_f32_16x16x32_bf16(
                        a2[kk][mf], bb[nf], acc[ei][mf][nf], 0, 0, 0);
        }
        __builtin_amdgcn_s_setprio(0);
        if ((s & 15) == 15) {                        // pair complete: fold both experts
            int ep = s >> 4;
            fold(ep * 2, acc[0]);
            fold(ep * 2 + 1, acc[1]);
        }
    }

    // ---- TI -> LDS (bf16), overlaying dead Xs/Bs
    __syncthreads();                                 // all waves done with Xs/Bs
    #pragma unroll
    for (int mf = 0; mf < 4; ++mf)
        #pragma unroll
        for (int nf = 0; nf < 2; ++nf)
            #pragma unroll
            for (int r = 0; r < 4; ++r) {
                int row = mf * 16 + l4 * 4 + r;
                int col = wv32 + nf * 16 + l15;
                TIs[(0 * 64 + row) * 264 + col] = f2bf(ti0[mf][nf][r]);
                TIs[(1 * 64 + row) * 264 + col] = f2bf(ti1[mf][nf][r]);
            }
    __syncthreads();

    // ---- tower: wave w -> task w>>2, rows (w&3)*16; N=64, K=256
    {
        int tt = wav >> 2, m0t = (wav & 3) * 16;
        f32x4 ac[4];
        #pragma unroll
        for (int nf = 0; nf < 4; ++nf) ac[nf] = z;
        #pragma unroll
        for (int kk = 0; kk < 8; ++kk) {
            int kcol = kk * 32 + l4 * 8;
            short8 a = *(const short8*)(TIs + ((size_t)(tt * 64 + m0t + l15)) * 264 + kcol);
            #pragma unroll
            for (int nf = 0; nf < 4; ++nf) {
                short8 b = *(const short8*)(WtT + ((size_t)tt * NO + nf * 16 + l15) * HE + kcol);
                ac[nf] = __builtin_amdgcn_mfma_f32_16x16x32_bf16(a, b, ac[nf], 0, 0, 0);
            }
        }
        #pragma unroll
        for (int nf = 0; nf < 4; ++nf) {
            int col = nf * 16 + l15;
            float bias = bt[tt * NO + col];
            #pragma unroll
            for (int r = 0; r < 4; ++r) {
                int row = r0 + m0t + l4 * 4 + r;
                float v = ac[nf][r] + bias;
                v = 1.f / (1.f + __expf(-v));
                out[(size_t)tt * (B_ * NO) + (size_t)row * NO + col] = v;
            }
        }
    }
}

extern "C" void kernel_launch(void* const* d_in, const int* in_sizes, int n_in,
                              void* d_out, int out_size, void* d_ws, size_t ws_size,
                              hipStream_t stream) {
    const float* xv = (const float*)d_in[0];
    const float* We = (const float*)d_in[1];
    const float* be = (const float*)d_in[2];
    const float* Wg = (const float*)d_in[3];
    const float* bg = (const float*)d_in[4];
    const float* Wt = (const float*)d_in[5];
    const float* bt = (const float*)d_in[6];
    float* out = (float*)d_out;

    char* w = (char*)d_ws;
    unsigned short* Wb  = (unsigned short*)(w);                 //  2 MiB
    unsigned short* WtT = (unsigned short*)(w + 2097152);       // 64 KiB
    unsigned short* WgT = (unsigned short*)(w + 2162688);       // 16 KiB

    k_cvt_w<<<265, 256, 0, stream>>>(We, Wt, Wg, Wb, WtT, WgT);
    k_mega<<<256, 512, 0, stream>>>(xv, Wb, be, WgT, bg, WtT, bt, out);
}

// Round 15
// 62.022 us; speedup vs baseline: 3.9724x; 3.9724x over previous
//
#include <hip/hip_runtime.h>
#include <hip/hip_bf16.h>

#define B_   16384
#define KIN  512
#define NE   8
#define HE   256
#define NT   2
#define NO   64

using f32x4  = __attribute__((ext_vector_type(4))) float;
using short8 = __attribute__((ext_vector_type(8))) short;

typedef const __attribute__((address_space(1))) void* gas_ptr;
typedef __attribute__((address_space(3))) void* las_ptr;

__device__ __forceinline__ float bf2f(unsigned short u) {
    union { unsigned int i; float f; } c; c.i = ((unsigned int)u) << 16; return c.f;
}
__device__ __forceinline__ unsigned short f2bf(float f) {
    union { __hip_bfloat16 h; unsigned short u; } c; c.h = __float2bfloat16(f); return c.u;
}

// ---------------- K_W: all weight preprocessing in one launch ----------------
__global__ __launch_bounds__(256) void k_cvt_w(const float* __restrict__ We,
                                               const float* __restrict__ Wt,
                                               const float* __restrict__ Wg,
                                               unsigned short* __restrict__ Wb,
                                               unsigned short* __restrict__ WtT,
                                               unsigned short* __restrict__ WgT) {
    int bid = blockIdx.x;
    int tid = threadIdx.x;
    if (bid < 256) {
        __shared__ float tile[64][65];
        int e = bid >> 5, rem = bid & 31, kt = rem >> 2, ht = rem & 3;
        const float* src = We + e * (KIN * HE) + (kt * 64) * HE + ht * 64;
        for (int it = 0; it < 16; ++it) {
            int idx = tid + it * 256;
            int i = idx >> 6, j = idx & 63;
            tile[i][j] = src[i * HE + j];
        }
        __syncthreads();
        unsigned short* dst = Wb + (size_t)(e * HE + ht * 64) * KIN + kt * 64;
        for (int it = 0; it < 16; ++it) {
            int idx = tid + it * 256;
            int i = idx >> 6, j = idx & 63;
            dst[i * KIN + j] = f2bf(tile[j][i]);
        }
    } else if (bid < 264) {
        __shared__ float tile[64][65];
        int b = bid - 256;
        int t = b >> 2, kt = b & 3, k0 = kt * 64;
        const float* src = Wt + t * (HE * NO) + k0 * NO;
        for (int it = 0; it < 16; ++it) {
            int idx = tid + it * 256;
            int i = idx >> 6, j = idx & 63;
            tile[i][j] = src[i * NO + j];
        }
        __syncthreads();
        unsigned short* dst = WtT + (size_t)t * NO * HE + k0;
        for (int it = 0; it < 16; ++it) {
            int idx = tid + it * 256;
            int o = idx >> 6, j = idx & 63;
            dst[o * HE + j] = f2bf(tile[j][o]);
        }
    } else {
        int n = tid >> 4;
        int kb = (tid & 15) * 32;
        int t = n >> 3, e = n & 7;
        const float* src = Wg + t * (KIN * NE) + e;
        for (int j = 0; j < 32; ++j) {
            int k = kb + j;
            WgT[n * KIN + k] = f2bf(src[k * NE]);
        }
    }
}

// ---------------- K_MEGA: cvt_x + gates + experts + mix + tower, fused ----------------
// VERBATIM round-10 structure (62.0 µs verified; VGPR 92, zero spill).
// 64-row stripe, 512 threads (8 waves), grid 256 = 1 block/CU.
// BARRIER-FREE expert loop: each wave stages ONLY its own 32-row B slice
// (rows [wv32, wv32+32) of each [256][64] tile) -> no cross-wave Bs dependency.
// Per-wave pacing: stage(s+1) [4 gload_lds]; s_waitcnt vmcnt(4) => batch s landed.
// Ring: 2 slots x 32 KB. Xs/gs read-only after the two prologue barriers.
// NOTE (r11-r14 falsified): any added loop-carried register state (B-in-regs,
// persistent A frags, doubled acc) tips the unified VGPR/AGPR file into scratch
// spill (82-865 MB WRITE). Keep loop state at acc32+ti64, VGPR ~92.
__global__ __launch_bounds__(512, 2) void k_mega(const float* __restrict__ xv,
                                                 const unsigned short* __restrict__ Wb,
                                                 const float* __restrict__ be,
                                                 const unsigned short* __restrict__ WgT,
                                                 const float* __restrict__ bg,
                                                 const unsigned short* __restrict__ WtT,
                                                 const float* __restrict__ bt,
                                                 float* __restrict__ out) {
    __shared__ __align__(16) char smem[135424];
    unsigned short* Xs  = (unsigned short*)smem;             // 65536 B, swizzled
    unsigned short* Bs  = (unsigned short*)(smem + 65536);   // 65536 B = 2 slots x 32KB
    float*          gs  = (float*)(smem + 131072);           // 4352 B, row stride 17
    unsigned short* TIs = (unsigned short*)smem;             // overlay after loop

    int tid = threadIdx.x, lane = tid & 63, wav = tid >> 6;
    int l15 = lane & 15, l4 = lane >> 4;
    int swz = (l15 & 7) * 8;                 // read-side XOR (shorts)
    int wv32 = wav * 32;                     // wave's h-col slice
    int r0 = blockIdx.x * 64;

    int row_off = lane >> 3;                 // 0..7
    int sco = ((lane & 7) ^ row_off) * 8;    // pre-swizzled source chunk (shorts)

    // wave stages ONLY its own 32-row slice of tile s into slot s&1
    auto stage_b = [&](int s) {
        int e = s >> 3, kt = s & 7, b = s & 1;
        const unsigned short* Wbase = Wb + (size_t)(e * 256 + wv32) * KIN + kt * 64;
        #pragma unroll
        for (int i = 0; i < 4; ++i) {
            int rb = i * 8;
            __builtin_amdgcn_global_load_lds(
                (gas_ptr)(Wbase + (size_t)(rb + row_off) * KIN + sco),
                (las_ptr)(Bs + b * 16384 + (wv32 + rb) * 64), 16, 0, 0);
        }
    };

    // ---- prologue: X fp32 -> bf16 -> swizzled LDS (reg-staged)
    #pragma unroll
    for (int j = 0; j < 8; ++j) {
        int row = wav * 8 + j;
        const float4* src = (const float4*)(xv + (size_t)(r0 + row) * KIN) + lane * 2;
        float4 xa = src[0], xb = src[1];
        union { short8 v; unsigned short s[8]; } cv;
        cv.s[0] = f2bf(xa.x); cv.s[1] = f2bf(xa.y); cv.s[2] = f2bf(xa.z); cv.s[3] = f2bf(xa.w);
        cv.s[4] = f2bf(xb.x); cv.s[5] = f2bf(xb.y); cv.s[6] = f2bf(xb.z); cv.s[7] = f2bf(xb.w);
        *(short8*)(Xs + row * KIN + ((lane ^ (row & 7)) * 8)) = cv.v;
    }
    asm volatile("s_waitcnt lgkmcnt(0)" ::: "memory");
    asm volatile("s_barrier" ::: "memory");          // Xs visible to all waves

    stage_b(0);                                      // lands during gates phase

    // ---- gates: softmax(X @ WgT^T + bg) -> gs  (waves w, w+4 duplicate; benign)
    {
        int m0w = (wav & 3) * 16;
        f32x4 ga = {0.f, 0.f, 0.f, 0.f};
        #pragma unroll
        for (int kk = 0; kk < 16; ++kk) {
            short8 a = *(const short8*)(Xs + (m0w + l15) * KIN + ((kk * 32 + l4 * 8) ^ swz));
            short8 b = *(const short8*)(WgT + (size_t)l15 * KIN + kk * 32 + l4 * 8);
            ga = __builtin_amdgcn_mfma_f32_16x16x32_bf16(a, b, ga, 0, 0, 0);
        }
        float bias = bg[l15];
        #pragma unroll
        for (int r = 0; r < 4; ++r) {
            float v = ga[r] + bias;
            float m = v;
            m = fmaxf(m, __shfl_xor(m, 1));
            m = fmaxf(m, __shfl_xor(m, 2));
            m = fmaxf(m, __shfl_xor(m, 4));
            float p = __expf(v - m);
            float su = p;
            su += __shfl_xor(su, 1);
            su += __shfl_xor(su, 2);
            su += __shfl_xor(su, 4);
            gs[(m0w + l4 * 4 + r) * 17 + l15] = p / su;
        }
    }
    asm volatile("s_waitcnt lgkmcnt(0)" ::: "memory");
    asm volatile("s_barrier" ::: "memory");          // gs visible to all waves

    // ---- expert loop state
    f32x4 acc[4][2];
    f32x4 ti0[4][2], ti1[4][2];
    f32x4 z = {0.f, 0.f, 0.f, 0.f};
    #pragma unroll
    for (int mf = 0; mf < 4; ++mf)
        #pragma unroll
        for (int nf = 0; nf < 2; ++nf) { acc[mf][nf] = z; ti0[mf][nf] = z; ti1[mf][nf] = z; }

    auto compute = [&](int s) {
        int k0 = (s & 7) * 64, b = s & 1;
        __builtin_amdgcn_s_setprio(1);
        #pragma unroll
        for (int kk = 0; kk < 2; ++kk) {
            short8 a[4], bb[2];
            int kca = (k0 + kk * 32 + l4 * 8) ^ swz;
            int kcb = (kk * 32 + l4 * 8) ^ swz;
            #pragma unroll
            for (int mf = 0; mf < 4; ++mf)
                a[mf] = *(const short8*)(Xs + (mf * 16 + l15) * KIN + kca);
            #pragma unroll
            for (int nf = 0; nf < 2; ++nf)
                bb[nf] = *(const short8*)(Bs + b * 16384 + (wv32 + nf * 16 + l15) * 64 + kcb);
            #pragma unroll
            for (int mf = 0; mf < 4; ++mf)
                #pragma unroll
                for (int nf = 0; nf < 2; ++nf)
                    acc[mf][nf] = __builtin_amdgcn_mfma_f32_16x16x32_bf16(a[mf], bb[nf], acc[mf][nf], 0, 0, 0);
        }
        __builtin_amdgcn_s_setprio(0);
    };
    auto fold = [&](int e) {
        float b0 = be[e * 256 + wv32 + l15];
        float b1 = be[e * 256 + wv32 + 16 + l15];
        #pragma unroll
        for (int mf = 0; mf < 4; ++mf) {
            #pragma unroll
            for (int r = 0; r < 4; ++r) {
                int rloc = mf * 16 + l4 * 4 + r;
                float g0 = gs[rloc * 17 + e];
                float g1 = gs[rloc * 17 + 8 + e];
                float h0 = fmaxf(acc[mf][0][r] + b0, 0.f);
                float h1 = fmaxf(acc[mf][1][r] + b1, 0.f);
                ti0[mf][0][r] = fmaf(g0, h0, ti0[mf][0][r]);
                ti0[mf][1][r] = fmaf(g0, h1, ti0[mf][1][r]);
                ti1[mf][0][r] = fmaf(g1, h0, ti1[mf][0][r]);
                ti1[mf][1][r] = fmaf(g1, h1, ti1[mf][1][r]);
                acc[mf][0][r] = 0.f;
                acc[mf][1][r] = 0.f;
            }
        }
    };

    // ---- main loop: BARRIER-FREE; per-wave counted vmcnt pacing
    #pragma unroll 8
    for (int s = 0; s < 64; ++s) {
        if (s < 63) {
            stage_b(s + 1);
            asm volatile("s_waitcnt vmcnt(4)" ::: "memory");  // batch s landed; s+1 in flight
        } else {
            asm volatile("s_waitcnt vmcnt(0)" ::: "memory");
        }
        compute(s);
        if ((s & 7) == 7) fold(s >> 3);
    }

    // ---- TI -> LDS (bf16), overlaying dead Xs/Bs
    __syncthreads();                                   // all waves done with Xs/Bs
    #pragma unroll
    for (int mf = 0; mf < 4; ++mf)
        #pragma unroll
        for (int nf = 0; nf < 2; ++nf)
            #pragma unroll
            for (int r = 0; r < 4; ++r) {
                int row = mf * 16 + l4 * 4 + r;
                int col = wv32 + nf * 16 + l15;
                TIs[(0 * 64 + row) * 264 + col] = f2bf(ti0[mf][nf][r]);
                TIs[(1 * 64 + row) * 264 + col] = f2bf(ti1[mf][nf][r]);
            }
    __syncthreads();

    // ---- tower: wave w -> task w>>2, rows (w&3)*16; N=64, K=256
    {
        int tt = wav >> 2, m0t = (wav & 3) * 16;
        f32x4 ac[4];
        #pragma unroll
        for (int nf = 0; nf < 4; ++nf) ac[nf] = z;
        #pragma unroll
        for (int kk = 0; kk < 8; ++kk) {
            int kcol = kk * 32 + l4 * 8;
            short8 a = *(const short8*)(TIs + ((size_t)(tt * 64 + m0t + l15)) * 264 + kcol);
            #pragma unroll
            for (int nf = 0; nf < 4; ++nf) {
                short8 b = *(const short8*)(WtT + ((size_t)tt * NO + nf * 16 + l15) * HE + kcol);
                ac[nf] = __builtin_amdgcn_mfma_f32_16x16x32_bf16(a, b, ac[nf], 0, 0, 0);
            }
        }
        #pragma unroll
        for (int nf = 0; nf < 4; ++nf) {
            int col = nf * 16 + l15;
            float bias = bt[tt * NO + col];
            #pragma unroll
            for (int r = 0; r < 4; ++r) {
                int row = r0 + m0t + l4 * 4 + r;
                float v = ac[nf][r] + bias;
                v = 1.f / (1.f + __expf(-v));
                out[(size_t)tt * (B_ * NO) + (size_t)row * NO + col] = v;
            }
        }
    }
}

extern "C" void kernel_launch(void* const* d_in, const int* in_sizes, int n_in,
                              void* d_out, int out_size, void* d_ws, size_t ws_size,
                              hipStream_t stream) {
    const float* xv = (const float*)d_in[0];
    const float* We = (const float*)d_in[1];
    const float* be = (const float*)d_in[2];
    const float* Wg = (const float*)d_in[3];
    const float* bg = (const float*)d_in[4];
    const float* Wt = (const float*)d_in[5];
    const float* bt = (const float*)d_in[6];
    float* out = (float*)d_out;

    char* w = (char*)d_ws;
    unsigned short* Wb  = (unsigned short*)(w);                 //  2 MiB
    unsigned short* WtT = (unsigned short*)(w + 2097152);       // 64 KiB
    unsigned short* WgT = (unsigned short*)(w + 2162688);       // 16 KiB

    k_cvt_w<<<265, 256, 0, stream>>>(We, Wt, Wg, Wb, WtT, WgT);
    k_mega<<<256, 512, 0, stream>>>(xv, Wb, be, WgT, bg, WtT, bt, out);
}